// Round 14
// baseline (289.931 us; speedup 1.0000x reference)
//
#include <hip/hip_runtime.h>
#include <stdint.h>

typedef __bf16 bf16;
typedef bf16 bf16x2 __attribute__((ext_vector_type(2)));
typedef bf16 bf16x8 __attribute__((ext_vector_type(8)));
typedef float f32x4 __attribute__((ext_vector_type(4)));
typedef float f32x16 __attribute__((ext_vector_type(16)));

static constexpr int B_    = 16;
static constexpr int C_IN  = 64;
static constexpr int H_    = 64;
static constexpr int W_    = 64;
static constexpr int C_OUT = 128;
static constexpr int NC    = 512;
static constexpr int PS    = 576;       // C_IN*3*3
static constexpr int L_    = H_ * W_;   // 4096
static constexpr int NR    = B_ * L_;   // 65536

#define DEVI __device__ __forceinline__

DEVI void gload_lds16(const void* g, void* l) {
  __builtin_amdgcn_global_load_lds(
      (const __attribute__((address_space(1))) uint32_t*)g,
      (__attribute__((address_space(3))) uint32_t*)l, 16, 0, 0);
}

// ---------------- prep kernels ----------------

__global__ void prep_w_kernel(const float* __restrict__ w, bf16* __restrict__ WB,
                              bf16* __restrict__ ccT) {
  int i = blockIdx.x * 256 + threadIdx.x;
  if (i < C_OUT * PS) WB[i] = (bf16)w[i];
  if (i < 64 * NC) ccT[(size_t)PS * NC + i] = (bf16)0.f;  // zero pad rows 576..639
}

__global__ void prep_cc_kernel(const float* __restrict__ cc, bf16* __restrict__ ccB,
                               bf16* __restrict__ ccT, float* __restrict__ cn) {
  int j = blockIdx.x;
  const float* src = cc + (size_t)j * PS;
  float s = 0.f;
  for (int p = threadIdx.x; p < PS; p += 256) {
    float v = src[p];
    bf16 bv = (bf16)v;
    ccB[(size_t)j * PS + p] = bv;
    ccT[(size_t)p * NC + j] = bv;
    float fv = (float)bv;
    s += fv * fv;
  }
  for (int o = 32; o; o >>= 1) s += __shfl_xor(s, o);
  __shared__ float red[4];
  int lane = threadIdx.x & 63, wid = threadIdx.x >> 6;
  if (lane == 0) red[wid] = s;
  __syncthreads();
  if (threadIdx.x == 0) cn[j] = red[0] + red[1] + red[2] + red[3];
}

// ---------------- patch: LDS-staged im2col + rownorm (round-10, verified) ------
static constexpr int XS_STRIDE = 66;
static constexpr int XS_PLANE  = 64 * XS_STRIDE;
static constexpr int XS_OFF    = 2;

__global__ void __launch_bounds__(256, 4) patch_kernel(
    const float* __restrict__ x, bf16* __restrict__ flatB,
    float* __restrict__ rn, float* __restrict__ rsum) {
  __shared__ bf16 xs[XS_OFF + 3 * XS_PLANE + 64];
  const int bh = blockIdx.x;
  const int b = bh >> 6, h = bh & 63;
  const size_t bOff = (size_t)b * (C_IN * L_);
#pragma unroll
  for (int it = 0; it < 12; ++it) {
    int idx = threadIdx.x + it * 256;
    int plane = idx >> 10;
    int rem = idx & 1023;
    int c = rem >> 4;
    int f4 = rem & 15;
    int y = h + plane - 1;
    int e = XS_OFF + plane * XS_PLANE + c * XS_STRIDE + f4 * 4;
    bf16x2 lo = {(bf16)0.f, (bf16)0.f}, hi = {(bf16)0.f, (bf16)0.f};
    if ((unsigned)y < 64u) {
      float4 v = *(const float4*)(x + bOff + (size_t)c * L_ + y * 64 + f4 * 4);
      lo = bf16x2{(bf16)v.x, (bf16)v.y};
      hi = bf16x2{(bf16)v.z, (bf16)v.w};
    }
    *(bf16x2*)(xs + e) = lo;
    *(bf16x2*)(xs + e + 2) = hi;
  }
  __syncthreads();

  const int lane = threadIdx.x & 63, wid = threadIdx.x >> 6;
  int eb[8], km[8];
#pragma unroll
  for (int q = 0; q < 8; q++) {
    int p = lane * 8 + q;
    int c = p / 9, r9 = p - c * 9;
    int kh = r9 / 3, kw = r9 - kh * 3;
    eb[q] = kh * XS_PLANE + c * XS_STRIDE + (kw - 1);
    km[q] = kw - 1;
  }
  int ebt[8], kmt[8];
  {
    int pl = (lane & 7) * 8;
#pragma unroll
    for (int q = 0; q < 8; q++) {
      int p = 512 + pl + q;
      int c = p / 9, r9 = p - c * 9;
      int kh = r9 / 3, kw = r9 - kh * 3;
      ebt[q] = kh * XS_PLANE + c * XS_STRIDE + (kw - 1);
      kmt[q] = kw - 1;
    }
  }
  for (int it = 0; it < 16; ++it) {
    int w = wid * 16 + it;
    int row = bh * 64 + w;
    bf16* outp = flatB + (size_t)row * PS;
    float s = 0.f;
    bf16x8 v;
#pragma unroll
    for (int q = 0; q < 8; q++) {
      int xx = w + km[q];
      float fv = ((unsigned)xx < 64u) ? (float)xs[XS_OFF + eb[q] + w] : 0.f;
      v[q] = (bf16)fv;
      s += fv * fv;
    }
    *(bf16x8*)(outp + lane * 8) = v;
    if (lane < 8) {
      bf16x8 v2;
#pragma unroll
      for (int q = 0; q < 8; q++) {
        int xx = w + kmt[q];
        float fv = ((unsigned)xx < 64u) ? (float)xs[XS_OFF + ebt[q] + w] : 0.f;
        v2[q] = (bf16)fv;
        s += fv * fv;
      }
      *(bf16x8*)(outp + 512 + lane * 8) = v2;
    }
    for (int o = 32; o; o >>= 1) s += __shfl_xor(s, o);
    if (lane == 0) { rn[row] = s; rsum[row] = 0.f; }
  }
}

// ---------------- NT-GEMM: r12 skeleton, 32x32x16 MFMA fragments ----------
// 128x128 tile, 4 waves (2m x 2n), wave-tile 64x64 = 2x2 frags of 32x32,
// BK=64 (4 k-steps of 16), single-buffer 2-barrier loop, 32 KB LDS,
// XOR slot swizzle (verified 0-conflict). acc = 2x2 x f32x16 = 64 regs.
// C/D layout (m74/m101, HW-verified): col=lane&31, row=(reg&3)+8*(reg>>2)+4*(lane>>5).
// EPI 1: E = exp(-t*dist) bf16 + atomicAdd row sums.  EPI 2: final in-place.
template <int EPI, int GX>
__global__ void __launch_bounds__(256, 4) gemm_nt(
    const bf16* __restrict__ A, int lda, const bf16* __restrict__ Bm, int ldb,
    int M, int N, int Kd,
    const float* __restrict__ e0, const float* __restrict__ e1,
    const float* __restrict__ e2, const bf16* flatB,
    float* outF, bf16* outB, int ldc) {
  const int blk = blockIdx.x;
  const int xcd = blk & 7;
  const int k = blk >> 3;
  const int ypx = (gridDim.x >> 3) / GX;
  const int bx = k % GX;
  const int by = xcd * ypx + k / GX;
  const int m0 = by * 128, n0 = bx * 128;

  __shared__ bf16 As[128 * 64];
  __shared__ bf16 Bs[128 * 64];
  const int tid = threadIdx.x;
  const int lane = tid & 63;
  const int wid = tid >> 6;
  const int wr = wid >> 1, wc = wid & 1;

  const int srow = tid >> 3;
  const int sch = ((tid & 7) ^ (srow & 7)) * 8;
  const bf16* gA = A + (size_t)(m0 + srow) * lda + sch;
  const bf16* gB = Bm + (size_t)(n0 + srow) * ldb + sch;
  bf16* lA = As + tid * 8;
  bf16* lB = Bs + tid * 8;

  // 32x32 fragment addressing: row-in-frag = lane&31, k-chunk = 2s + (lane>>5)
  const int l31 = lane & 31;
  const int khalf = lane >> 5;          // 0/1
  const int arow0 = (wr * 64 + l31) * 64;        // + fi*32*64
  const int brow0 = (wc * 64 + l31) * 64;        // + fj*32*64
  const int axor0 = l31 & 7;

  f32x16 acc[2][2];
#pragma unroll
  for (int i = 0; i < 2; i++)
#pragma unroll
    for (int j = 0; j < 2; j++)
#pragma unroll
      for (int r = 0; r < 16; r++) acc[i][j][r] = 0.f;

  const int nk = Kd >> 6;
  for (int kt = 0; kt < nk; ++kt) {
    __syncthreads();
    const bf16* ga = gA + kt * 64;
    const bf16* gb = gB + kt * 64;
#pragma unroll
    for (int q = 0; q < 4; ++q) {
      gload_lds16(ga + (size_t)(q * 32) * lda, lA + q * 2048);
      gload_lds16(gb + (size_t)(q * 32) * ldb, lB + q * 2048);
    }
    __syncthreads();  // drains vmcnt -> LDS tile ready
#pragma unroll
    for (int s = 0; s < 4; ++s) {
      const int chunk = 2 * s + khalf;
      bf16x8 af[2], bf[2];
#pragma unroll
      for (int i = 0; i < 2; i++) {
        int row = wr * 64 + i * 32 + l31;
        af[i] = *(const bf16x8*)(As + arow0 + i * 2048 + ((chunk ^ (row & 7)) * 8));
      }
#pragma unroll
      for (int j = 0; j < 2; j++) {
        int row = wc * 64 + j * 32 + l31;
        bf[j] = *(const bf16x8*)(Bs + brow0 + j * 2048 + ((chunk ^ (row & 7)) * 8));
      }
#pragma unroll
      for (int i = 0; i < 2; i++)
#pragma unroll
        for (int j = 0; j < 2; j++)
          acc[i][j] = __builtin_amdgcn_mfma_f32_32x32x16_bf16(af[i], bf[j], acc[i][j], 0, 0, 0);
    }
  }

  // D mapping: row = rbase + fi*32 + (reg&3) + 8*(reg>>2) + 4*khalf; col = cbase + fj*32 + l31
  const int rbase = m0 + wr * 64 + 4 * khalf;
  const int cbase = n0 + wc * 64 + l31;
  if constexpr (EPI == 1) {
    // e0 = rn, e1 = cn, e2 = temp; outB = E (bf16), outF = rsum (fp32 atomics)
    float t = e2[0];
    float cnv[2];
#pragma unroll
    for (int j = 0; j < 2; j++) cnv[j] = e1[cbase + j * 32];
#pragma unroll
    for (int i = 0; i < 2; i++) {
#pragma unroll
      for (int rg = 0; rg < 16; rg++) {
        int row = rbase + i * 32 + (rg & 3) + 8 * (rg >> 2);
        float rnv = e0[row];
        float es = 0.f;
#pragma unroll
        for (int j = 0; j < 2; j++) {
          float d2 = rnv + cnv[j] - 2.f * acc[i][j][rg];
          float e = __expf(-t * sqrtf(fmaxf(d2, 0.f)));
          outB[(size_t)row * ldc + cbase + j * 32] = (bf16)e;
          es += e;
        }
        es += __shfl_xor(es, 1);
        es += __shfl_xor(es, 2);
        es += __shfl_xor(es, 4);
        es += __shfl_xor(es, 8);
        es += __shfl_xor(es, 16);
        if (l31 == 0) atomicAdd(outF + row, es);
      }
    }
  } else {
    // EPI 2: e0 = temp, e1 = rsum; flatB = flat (read), outB = flat (in-place)
    float t = e0[0];
    float inv = 1.f / (t + 1.f);
#pragma unroll
    for (int i = 0; i < 2; i++) {
#pragma unroll
      for (int rg = 0; rg < 16; rg++) {
        int row = rbase + i * 32 + (rg & 3) + 8 * (rg >> 2);
        float arw = t * inv / e1[row];
#pragma unroll
        for (int j = 0; j < 2; j++) {
          int col = cbase + j * 32;
          if (col < N) {
            float fl = (float)flatB[(size_t)row * PS + col];
            float v = acc[i][j][rg] * arw + fl * inv;
            outB[(size_t)row * ldc + col] = (bf16)v;
          }
        }
      }
    }
  }
}

// ---------------- gemm3: fused reinterpret-transpose + mask + conv (r12) ------
__global__ void __launch_bounds__(256, 4) gemm3_kernel(
    const bf16* __restrict__ A, const bf16* __restrict__ F,
    const float* __restrict__ bias, float* __restrict__ outF) {
  const size_t bz = blockIdx.z;
  const bf16* Fb = F + bz * (size_t)L_ * PS;   // viewed [576][4096]
  float* outp = outF + bz * (size_t)C_OUT * L_;
  const int n0 = blockIdx.x * 128;

  __shared__ bf16 As[128 * 64];
  __shared__ bf16 Bs[128 * 64];
  const int tid = threadIdx.x;
  const int lane = tid & 63;
  const int wid = tid >> 6;
  const int wr = wid >> 1, wc = wid & 1;

  const int srow = tid >> 3;
  const int sch = ((tid & 7) ^ (srow & 7)) * 8;
  const bf16* gA = A + (size_t)srow * PS + sch;
  bf16* lA = As + tid * 8;

  const int lrow = lane & 15;
  const int kq = lane >> 4;
  const int axor = lrow & 7;
  const int arow = (wr * 64 + lrow) * 64;
  const int brow = (wc * 64 + lrow) * 64;

  f32x4 acc[4][4];
#pragma unroll
  for (int i = 0; i < 4; i++)
#pragma unroll
    for (int j = 0; j < 4; j++) acc[i][j] = f32x4{0.f, 0.f, 0.f, 0.f};

  const int nk = PS / 64;   // 9
  for (int kt = 0; kt < nk; ++kt) {
    __syncthreads();
    const bf16* ga = gA + kt * 64;
#pragma unroll
    for (int q = 0; q < 4; ++q)
      gload_lds16(ga + (size_t)(q * 32) * PS, lA + q * 2048);
#pragma unroll
    for (int ps = 0; ps < 2; ++ps) {
      int id = tid + ps * 256;
      int pp = id >> 4;
      int lc = id & 15;
      int pl = 2 * pp;
      int pg = kt * 64 + pl;
      const bf16* s0 = Fb + (size_t)pg * L_ + n0 + lc * 8;
      bf16x8 v0 = *(const bf16x8*)s0;
      bf16x8 v1 = *(const bf16x8*)(s0 + L_);
      int l8 = n0 + lc * 8;
      int oh = l8 >> 6;
      bool ow0 = (l8 & 63) == 0;
      int r90 = pg % 9;
      int kh0 = r90 / 3, kw0 = r90 - 3 * kh0;
      int r91 = (pg + 1) % 9;
      int kh1 = r91 / 3, kw1 = r91 - 3 * kh1;
      if (oh == 0 && kh0 == 0) {
#pragma unroll
        for (int e = 0; e < 8; e++) v0[e] = (bf16)0.f;
      }
      if (ow0 && kw0 == 0) v0[0] = (bf16)0.f;
      if (oh == 0 && kh1 == 0) {
#pragma unroll
        for (int e = 0; e < 8; e++) v1[e] = (bf16)0.f;
      }
      if (ow0 && kw1 == 0) v1[0] = (bf16)0.f;
#pragma unroll
      for (int e = 0; e < 8; ++e) {
        int l = lc * 8 + e;
        int addr = l * 64 + (((pl >> 3) ^ (l & 7)) << 3) + (pl & 7);
        *(bf16x2*)(Bs + addr) = bf16x2{v0[e], v1[e]};
      }
    }
    __syncthreads();
#pragma unroll
    for (int h = 0; h < 2; ++h) {
      const int cs = ((h * 4 + kq) ^ axor) * 8;
      bf16x8 af[4], bfr[4];
#pragma unroll
      for (int i = 0; i < 4; i++) af[i] = *(const bf16x8*)(As + arow + i * 1024 + cs);
#pragma unroll
      for (int j = 0; j < 4; j++) bfr[j] = *(const bf16x8*)(Bs + brow + j * 1024 + cs);
#pragma unroll
      for (int i = 0; i < 4; i++)
#pragma unroll
        for (int j = 0; j < 4; j++)
          acc[i][j] = __builtin_amdgcn_mfma_f32_16x16x32_bf16(af[i], bfr[j], acc[i][j], 0, 0, 0);
    }
  }

  const int rb = wr * 64 + kq * 4;
  const int cb = n0 + wc * 64 + lrow;
#pragma unroll
  for (int i = 0; i < 4; i++) {
#pragma unroll
    for (int j = 0; j < 4; j++) {
      int col = cb + j * 16;
#pragma unroll
      for (int r = 0; r < 4; r++) {
        int row = rb + i * 16 + r;
        outp[(size_t)row * L_ + col] = acc[i][j][r] + bias[row];
      }
    }
  }
}

// ---------------- launch ----------------

extern "C" void kernel_launch(void* const* d_in, const int* in_sizes, int n_in,
                              void* d_out, int out_size, void* d_ws, size_t ws_size,
                              hipStream_t stream) {
  (void)in_sizes; (void)n_in; (void)out_size; (void)ws_size;
  const float* x    = (const float*)d_in[0];
  const float* cc   = (const float*)d_in[1];
  const float* tp   = (const float*)d_in[2];
  const float* w    = (const float*)d_in[3];
  const float* bias = (const float*)d_in[4];
  float* out = (float*)d_out;

  char* ws = (char*)d_ws;
  size_t off = 0;
  auto alloc = [&](size_t bytes) {
    char* p = ws + off;
    off += (bytes + 255) & ~(size_t)255;
    return p;
  };
  bf16* ccB   = (bf16*)alloc((size_t)NC * PS * 2);        // 0.59 MB
  bf16* ccT   = (bf16*)alloc((size_t)640 * NC * 2);       // 0.66 MB (576 + 64 zero pad)
  float* cn   = (float*)alloc((size_t)NC * 4);
  bf16* WB    = (bf16*)alloc((size_t)C_OUT * PS * 2);     // 0.15 MB
  float* rn   = (float*)alloc((size_t)NR * 4);            // 0.26 MB
  float* rsum = (float*)alloc((size_t)NR * 4);            // 0.26 MB
  bf16* flatB = (bf16*)alloc((size_t)NR * PS * 2);        // 75.5 MB (final in-place)
  bf16* E     = (bf16*)alloc((size_t)NR * NC * 2);        // 67.1 MB
  // total ~= 145 MB  (ws_size = 256 MiB)

  prep_w_kernel<<<dim3(288), dim3(256), 0, stream>>>(w, WB, ccT);
  prep_cc_kernel<<<dim3(NC), dim3(256), 0, stream>>>(cc, ccB, ccT, cn);
  patch_kernel<<<dim3(B_ * H_), dim3(256), 0, stream>>>(x, flatB, rn, rsum);
  // GEMM1 (+softmax numerator): E = exp(-t*sqrt(max(rn+cn-2*flat@cc^T,0))), rsum += rows
  gemm_nt<1, 4><<<dim3((NC / 128) * (NR / 128)), dim3(256), 0, stream>>>(
      flatB, PS, ccB, PS, NR, NC, PS, rn, cn, tp, nullptr, rsum, E, NC);
  // GEMM2: flat <- (t*(E@cc)/rsum + flat)/(t+1)   (in-place)
  gemm_nt<2, 5><<<dim3(5 * (NR / 128)), dim3(256), 0, stream>>>(
      E, NC, ccT, NC, NR, PS, NC, tp, rsum, nullptr, flatB, nullptr, flatB, PS);
  // GEMM3 (batched, fused transpose+mask): out[b] = W' @ (mask o view(final_b)) + bias
  gemm3_kernel<<<dim3(L_ / 128, 1, B_), dim3(256), 0, stream>>>(WB, flatB, bias, out);
}

// Round 15
// 241.438 us; speedup vs baseline: 1.2008x; 1.2008x over previous
//
#include <hip/hip_runtime.h>
#include <stdint.h>

typedef __bf16 bf16;
typedef bf16 bf16x2 __attribute__((ext_vector_type(2)));
typedef bf16 bf16x8 __attribute__((ext_vector_type(8)));
typedef float f32x4 __attribute__((ext_vector_type(4)));

static constexpr int B_    = 16;
static constexpr int C_IN  = 64;
static constexpr int H_    = 64;
static constexpr int W_    = 64;
static constexpr int C_OUT = 128;
static constexpr int NC    = 512;
static constexpr int PS    = 576;       // C_IN*3*3
static constexpr int L_    = H_ * W_;   // 4096
static constexpr int NR    = B_ * L_;   // 65536

#define DEVI __device__ __forceinline__

DEVI void gload_lds16(const void* g, void* l) {
  __builtin_amdgcn_global_load_lds(
      (const __attribute__((address_space(1))) uint32_t*)g,
      (__attribute__((address_space(3))) uint32_t*)l, 16, 0, 0);
}

// ---------------- prep kernels ----------------

__global__ void prep_w_kernel(const float* __restrict__ w, bf16* __restrict__ WB,
                              bf16* __restrict__ ccT) {
  int i = blockIdx.x * 256 + threadIdx.x;
  if (i < C_OUT * PS) WB[i] = (bf16)w[i];
  if (i < 64 * NC) ccT[(size_t)PS * NC + i] = (bf16)0.f;  // zero pad rows 576..639
}

__global__ void prep_cc_kernel(const float* __restrict__ cc, bf16* __restrict__ ccB,
                               bf16* __restrict__ ccT, float* __restrict__ cn) {
  int j = blockIdx.x;
  const float* src = cc + (size_t)j * PS;
  float s = 0.f;
  for (int p = threadIdx.x; p < PS; p += 256) {
    float v = src[p];
    bf16 bv = (bf16)v;
    ccB[(size_t)j * PS + p] = bv;
    ccT[(size_t)p * NC + j] = bv;
    float fv = (float)bv;
    s += fv * fv;
  }
  for (int o = 32; o; o >>= 1) s += __shfl_xor(s, o);
  __shared__ float red[4];
  int lane = threadIdx.x & 63, wid = threadIdx.x >> 6;
  if (lane == 0) red[wid] = s;
  __syncthreads();
  if (threadIdx.x == 0) cn[j] = red[0] + red[1] + red[2] + red[3];
}

// ---------------- patch: LDS-staged im2col + rownorm ----------------
// (256,6): 12 VGPR / 26KB LDS -> 6 blocks/CU (156<=160KB LDS, reg cap 85>>12).
static constexpr int XS_STRIDE = 66;
static constexpr int XS_PLANE  = 64 * XS_STRIDE;
static constexpr int XS_OFF    = 2;

__global__ void __launch_bounds__(256, 6) patch_kernel(
    const float* __restrict__ x, bf16* __restrict__ flatB,
    float* __restrict__ rn, float* __restrict__ rsum) {
  __shared__ bf16 xs[XS_OFF + 3 * XS_PLANE + 64];
  const int bh = blockIdx.x;
  const int b = bh >> 6, h = bh & 63;
  const size_t bOff = (size_t)b * (C_IN * L_);
#pragma unroll
  for (int it = 0; it < 12; ++it) {
    int idx = threadIdx.x + it * 256;
    int plane = idx >> 10;
    int rem = idx & 1023;
    int c = rem >> 4;
    int f4 = rem & 15;
    int y = h + plane - 1;
    int e = XS_OFF + plane * XS_PLANE + c * XS_STRIDE + f4 * 4;
    bf16x2 lo = {(bf16)0.f, (bf16)0.f}, hi = {(bf16)0.f, (bf16)0.f};
    if ((unsigned)y < 64u) {
      float4 v = *(const float4*)(x + bOff + (size_t)c * L_ + y * 64 + f4 * 4);
      lo = bf16x2{(bf16)v.x, (bf16)v.y};
      hi = bf16x2{(bf16)v.z, (bf16)v.w};
    }
    *(bf16x2*)(xs + e) = lo;
    *(bf16x2*)(xs + e + 2) = hi;
  }
  __syncthreads();

  const int lane = threadIdx.x & 63, wid = threadIdx.x >> 6;
  int eb[8], km[8];
#pragma unroll
  for (int q = 0; q < 8; q++) {
    int p = lane * 8 + q;
    int c = p / 9, r9 = p - c * 9;
    int kh = r9 / 3, kw = r9 - kh * 3;
    eb[q] = kh * XS_PLANE + c * XS_STRIDE + (kw - 1);
    km[q] = kw - 1;
  }
  int ebt[8], kmt[8];
  {
    int pl = (lane & 7) * 8;
#pragma unroll
    for (int q = 0; q < 8; q++) {
      int p = 512 + pl + q;
      int c = p / 9, r9 = p - c * 9;
      int kh = r9 / 3, kw = r9 - kh * 3;
      ebt[q] = kh * XS_PLANE + c * XS_STRIDE + (kw - 1);
      kmt[q] = kw - 1;
    }
  }
  for (int it = 0; it < 16; ++it) {
    int w = wid * 16 + it;
    int row = bh * 64 + w;
    bf16* outp = flatB + (size_t)row * PS;
    float s = 0.f;
    bf16x8 v;
#pragma unroll
    for (int q = 0; q < 8; q++) {
      int xx = w + km[q];
      float fv = ((unsigned)xx < 64u) ? (float)xs[XS_OFF + eb[q] + w] : 0.f;
      v[q] = (bf16)fv;
      s += fv * fv;
    }
    *(bf16x8*)(outp + lane * 8) = v;
    if (lane < 8) {
      bf16x8 v2;
#pragma unroll
      for (int q = 0; q < 8; q++) {
        int xx = w + kmt[q];
        float fv = ((unsigned)xx < 64u) ? (float)xs[XS_OFF + ebt[q] + w] : 0.f;
        v2[q] = (bf16)fv;
        s += fv * fv;
      }
      *(bf16x8*)(outp + 512 + lane * 8) = v2;
    }
    for (int o = 32; o; o >>= 1) s += __shfl_xor(s, o);
    if (lane == 0) { rn[row] = s; rsum[row] = 0.f; }
  }
}

// ---------------- NT-GEMM (r12 best, verbatim) ----------------
// Single-buffer BK=64, 2 __syncthreads per K-step, 32 KB LDS, (256,4).
// LDS [128][64]: slot s of row r holds global k-chunk (s ^ (r&7));
// write side via pre-swizzled global source, read side same XOR (0 conflicts).
// EPI 1: E = exp(-t*dist) bf16 + atomicAdd row sums.  EPI 2: final in-place.
template <int EPI, int GX = 0>
__global__ void __launch_bounds__(256, 4) gemm_nt(
    const bf16* __restrict__ A, int lda, const bf16* __restrict__ Bm, int ldb,
    int M, int N, int Kd,
    const float* __restrict__ e0, const float* __restrict__ e1,
    const float* __restrict__ e2, const bf16* flatB,
    float* outF, bf16* outB, int ldc) {
  int bx, by;
  if constexpr (GX > 0) {
    int b = blockIdx.x;
    int xcd = b & 7;
    int k = b >> 3;
    int ypx = (gridDim.x >> 3) / GX;
    bx = k % GX;
    by = xcd * ypx + k / GX;
  } else {
    bx = blockIdx.x;
    by = blockIdx.y;
  }
  __shared__ bf16 As[128 * 64];
  __shared__ bf16 Bs[128 * 64];
  const int tid = threadIdx.x;
  const int lane = tid & 63;
  const int wid = tid >> 6;
  const int wr = wid >> 1, wc = wid & 1;
  const int m0 = by * 128, n0 = bx * 128;

  const int srow = tid >> 3;
  const int sch = ((tid & 7) ^ (srow & 7)) * 8;
  const bf16* gA = A + (size_t)(m0 + srow) * lda + sch;
  const bf16* gB = Bm + (size_t)(n0 + srow) * ldb + sch;
  bf16* lA = As + tid * 8;
  bf16* lB = Bs + tid * 8;

  const int lrow = lane & 15;
  const int kq = lane >> 4;
  const int axor = lrow & 7;
  const int arow = (wr * 64 + lrow) * 64;
  const int brow = (wc * 64 + lrow) * 64;

  f32x4 acc[4][4];
#pragma unroll
  for (int i = 0; i < 4; i++)
#pragma unroll
    for (int j = 0; j < 4; j++) acc[i][j] = f32x4{0.f, 0.f, 0.f, 0.f};

  const int nk = Kd >> 6;
  for (int kt = 0; kt < nk; ++kt) {
    __syncthreads();
    const bf16* ga = gA + kt * 64;
    const bf16* gb = gB + kt * 64;
#pragma unroll
    for (int q = 0; q < 4; ++q) {
      gload_lds16(ga + (size_t)(q * 32) * lda, lA + q * 2048);
      gload_lds16(gb + (size_t)(q * 32) * ldb, lB + q * 2048);
    }
    __syncthreads();
#pragma unroll
    for (int h = 0; h < 2; ++h) {
      const int cs = ((h * 4 + kq) ^ axor) * 8;
      bf16x8 af[4], bfr[4];
#pragma unroll
      for (int i = 0; i < 4; i++) af[i] = *(const bf16x8*)(As + arow + i * 1024 + cs);
#pragma unroll
      for (int j = 0; j < 4; j++) bfr[j] = *(const bf16x8*)(Bs + brow + j * 1024 + cs);
#pragma unroll
      for (int i = 0; i < 4; i++)
#pragma unroll
        for (int j = 0; j < 4; j++)
          acc[i][j] = __builtin_amdgcn_mfma_f32_16x16x32_bf16(af[i], bfr[j], acc[i][j], 0, 0, 0);
    }
  }

  const int rb = m0 + wr * 64 + kq * 4;
  const int cb = n0 + wc * 64 + lrow;
  if constexpr (EPI == 1) {
    float t = e2[0];
#pragma unroll
    for (int i = 0; i < 4; i++) {
      float rowsum[4] = {0.f, 0.f, 0.f, 0.f};
#pragma unroll
      for (int j = 0; j < 4; j++) {
        int col = cb + j * 16;
        float cnv = e1[col];
#pragma unroll
        for (int r = 0; r < 4; r++) {
          int row = rb + i * 16 + r;
          float d2 = e0[row] + cnv - 2.f * acc[i][j][r];
          float e = __expf(-t * sqrtf(fmaxf(d2, 0.f)));
          outB[(size_t)row * ldc + col] = (bf16)e;
          rowsum[r] += e;
        }
      }
#pragma unroll
      for (int r = 0; r < 4; r++) {
        float s = rowsum[r];
        s += __shfl_xor(s, 1);
        s += __shfl_xor(s, 2);
        s += __shfl_xor(s, 4);
        s += __shfl_xor(s, 8);
        if (lrow == 0) atomicAdd(outF + rb + i * 16 + r, s);
      }
    }
  } else {
    float t = e0[0];
    float inv = 1.f / (t + 1.f);
#pragma unroll
    for (int i = 0; i < 4; i++) {
      float arw[4];
#pragma unroll
      for (int r = 0; r < 4; r++) arw[r] = t * inv / e1[rb + i * 16 + r];
#pragma unroll
      for (int j = 0; j < 4; j++) {
        int col = cb + j * 16;
        if (col < N) {
#pragma unroll
          for (int r = 0; r < 4; r++) {
            int row = rb + i * 16 + r;
            float fl = (float)flatB[(size_t)row * PS + col];
            float v = acc[i][j][r] * arw[r] + fl * inv;
            outB[(size_t)row * ldc + col] = (bf16)v;
          }
        }
      }
    }
  }
}

// ---------------- gemm3: fused reinterpret-transpose + mask + conv (r12) ------
__global__ void __launch_bounds__(256, 4) gemm3_kernel(
    const bf16* __restrict__ A, const bf16* __restrict__ F,
    const float* __restrict__ bias, float* __restrict__ outF) {
  const size_t bz = blockIdx.z;
  const bf16* Fb = F + bz * (size_t)L_ * PS;   // viewed [576][4096]
  float* outp = outF + bz * (size_t)C_OUT * L_;
  const int n0 = blockIdx.x * 128;

  __shared__ bf16 As[128 * 64];
  __shared__ bf16 Bs[128 * 64];
  const int tid = threadIdx.x;
  const int lane = tid & 63;
  const int wid = tid >> 6;
  const int wr = wid >> 1, wc = wid & 1;

  const int srow = tid >> 3;
  const int sch = ((tid & 7) ^ (srow & 7)) * 8;
  const bf16* gA = A + (size_t)srow * PS + sch;
  bf16* lA = As + tid * 8;

  const int lrow = lane & 15;
  const int kq = lane >> 4;
  const int axor = lrow & 7;
  const int arow = (wr * 64 + lrow) * 64;
  const int brow = (wc * 64 + lrow) * 64;

  f32x4 acc[4][4];
#pragma unroll
  for (int i = 0; i < 4; i++)
#pragma unroll
    for (int j = 0; j < 4; j++) acc[i][j] = f32x4{0.f, 0.f, 0.f, 0.f};

  const int nk = PS / 64;   // 9
  for (int kt = 0; kt < nk; ++kt) {
    __syncthreads();
    const bf16* ga = gA + kt * 64;
#pragma unroll
    for (int q = 0; q < 4; ++q)
      gload_lds16(ga + (size_t)(q * 32) * PS, lA + q * 2048);
#pragma unroll
    for (int ps = 0; ps < 2; ++ps) {
      int id = tid + ps * 256;
      int pp = id >> 4;
      int lc = id & 15;
      int pl = 2 * pp;
      int pg = kt * 64 + pl;
      const bf16* s0 = Fb + (size_t)pg * L_ + n0 + lc * 8;
      bf16x8 v0 = *(const bf16x8*)s0;
      bf16x8 v1 = *(const bf16x8*)(s0 + L_);
      int l8 = n0 + lc * 8;
      int oh = l8 >> 6;
      bool ow0 = (l8 & 63) == 0;
      int r90 = pg % 9;
      int kh0 = r90 / 3, kw0 = r90 - 3 * kh0;
      int r91 = (pg + 1) % 9;
      int kh1 = r91 / 3, kw1 = r91 - 3 * kh1;
      if (oh == 0 && kh0 == 0) {
#pragma unroll
        for (int e = 0; e < 8; e++) v0[e] = (bf16)0.f;
      }
      if (ow0 && kw0 == 0) v0[0] = (bf16)0.f;
      if (oh == 0 && kh1 == 0) {
#pragma unroll
        for (int e = 0; e < 8; e++) v1[e] = (bf16)0.f;
      }
      if (ow0 && kw1 == 0) v1[0] = (bf16)0.f;
#pragma unroll
      for (int e = 0; e < 8; ++e) {
        int l = lc * 8 + e;
        int addr = l * 64 + (((pl >> 3) ^ (l & 7)) << 3) + (pl & 7);
        *(bf16x2*)(Bs + addr) = bf16x2{v0[e], v1[e]};
      }
    }
    __syncthreads();
#pragma unroll
    for (int h = 0; h < 2; ++h) {
      const int cs = ((h * 4 + kq) ^ axor) * 8;
      bf16x8 af[4], bfr[4];
#pragma unroll
      for (int i = 0; i < 4; i++) af[i] = *(const bf16x8*)(As + arow + i * 1024 + cs);
#pragma unroll
      for (int j = 0; j < 4; j++) bfr[j] = *(const bf16x8*)(Bs + brow + j * 1024 + cs);
#pragma unroll
      for (int i = 0; i < 4; i++)
#pragma unroll
        for (int j = 0; j < 4; j++)
          acc[i][j] = __builtin_amdgcn_mfma_f32_16x16x32_bf16(af[i], bfr[j], acc[i][j], 0, 0, 0);
    }
  }

  const int rb = wr * 64 + kq * 4;
  const int cb = n0 + wc * 64 + lrow;
#pragma unroll
  for (int i = 0; i < 4; i++) {
#pragma unroll
    for (int j = 0; j < 4; j++) {
      int col = cb + j * 16;
#pragma unroll
      for (int r = 0; r < 4; r++) {
        int row = rb + i * 16 + r;
        outp[(size_t)row * L_ + col] = acc[i][j][r] + bias[row];
      }
    }
  }
}

// ---------------- launch ----------------

extern "C" void kernel_launch(void* const* d_in, const int* in_sizes, int n_in,
                              void* d_out, int out_size, void* d_ws, size_t ws_size,
                              hipStream_t stream) {
  (void)in_sizes; (void)n_in; (void)out_size; (void)ws_size;
  const float* x    = (const float*)d_in[0];
  const float* cc   = (const float*)d_in[1];
  const float* tp   = (const float*)d_in[2];
  const float* w    = (const float*)d_in[3];
  const float* bias = (const float*)d_in[4];
  float* out = (float*)d_out;

  char* ws = (char*)d_ws;
  size_t off = 0;
  auto alloc = [&](size_t bytes) {
    char* p = ws + off;
    off += (bytes + 255) & ~(size_t)255;
    return p;
  };
  bf16* ccB   = (bf16*)alloc((size_t)NC * PS * 2);        // 0.59 MB
  bf16* ccT   = (bf16*)alloc((size_t)640 * NC * 2);       // 0.66 MB (576 + 64 zero pad)
  float* cn   = (float*)alloc((size_t)NC * 4);
  bf16* WB    = (bf16*)alloc((size_t)C_OUT * PS * 2);     // 0.15 MB
  float* rn   = (float*)alloc((size_t)NR * 4);            // 0.26 MB
  float* rsum = (float*)alloc((size_t)NR * 4);            // 0.26 MB
  bf16* flatB = (bf16*)alloc((size_t)NR * PS * 2);        // 75.5 MB (final in-place)
  bf16* E     = (bf16*)alloc((size_t)NR * NC * 2);        // 67.1 MB
  // total ~= 145 MB  (ws_size = 256 MiB)

  prep_w_kernel<<<dim3(288), dim3(256), 0, stream>>>(w, WB, ccT);
  prep_cc_kernel<<<dim3(NC), dim3(256), 0, stream>>>(cc, ccB, ccT, cn);
  patch_kernel<<<dim3(B_ * H_), dim3(256), 0, stream>>>(x, flatB, rn, rsum);
  // GEMM1 (+softmax numerator): E = exp(-t*sqrt(max(rn+cn-2*flat@cc^T,0))), rsum += rows
  gemm_nt<1, 4><<<dim3((NC / 128) * (NR / 128)), dim3(256), 0, stream>>>(
      flatB, PS, ccB, PS, NR, NC, PS, rn, cn, tp, nullptr, rsum, E, NC);
  // GEMM2: flat <- (t*(E@cc)/rsum + flat)/(t+1)   (in-place)
  gemm_nt<2, 5><<<dim3(5 * (NR / 128)), dim3(256), 0, stream>>>(
      E, NC, ccT, NC, NR, PS, NC, tp, rsum, nullptr, flatB, nullptr, flatB, PS);
  // GEMM3 (batched, fused transpose+mask): out[b] = W' @ (mask o view(final_b)) + bias
  gemm3_kernel<<<dim3(L_ / 128, 1, B_), dim3(256), 0, stream>>>(WB, flatB, bias, out);
}

// Round 16
// 241.228 us; speedup vs baseline: 1.2019x; 1.0009x over previous
//
#include <hip/hip_runtime.h>
#include <stdint.h>

typedef __bf16 bf16;
typedef bf16 bf16x2 __attribute__((ext_vector_type(2)));
typedef bf16 bf16x8 __attribute__((ext_vector_type(8)));
typedef float f32x4 __attribute__((ext_vector_type(4)));

static constexpr int B_    = 16;
static constexpr int C_IN  = 64;
static constexpr int H_    = 64;
static constexpr int W_    = 64;
static constexpr int C_OUT = 128;
static constexpr int NC    = 512;
static constexpr int PS    = 576;       // C_IN*3*3
static constexpr int L_    = H_ * W_;   // 4096
static constexpr int NR    = B_ * L_;   // 65536

#define DEVI __device__ __forceinline__

DEVI void gload_lds16(const void* g, void* l) {
  __builtin_amdgcn_global_load_lds(
      (const __attribute__((address_space(1))) uint32_t*)g,
      (__attribute__((address_space(3))) uint32_t*)l, 16, 0, 0);
}

// ---------------- prep kernels ----------------

__global__ void prep_w_kernel(const float* __restrict__ w, bf16* __restrict__ WB,
                              bf16* __restrict__ ccT) {
  int i = blockIdx.x * 256 + threadIdx.x;
  if (i < C_OUT * PS) WB[i] = (bf16)w[i];
  if (i < 64 * NC) ccT[(size_t)PS * NC + i] = (bf16)0.f;  // zero pad rows 576..639
}

__global__ void prep_cc_kernel(const float* __restrict__ cc, bf16* __restrict__ ccB,
                               bf16* __restrict__ ccT, float* __restrict__ cn) {
  int j = blockIdx.x;
  const float* src = cc + (size_t)j * PS;
  float s = 0.f;
  for (int p = threadIdx.x; p < PS; p += 256) {
    float v = src[p];
    bf16 bv = (bf16)v;
    ccB[(size_t)j * PS + p] = bv;
    ccT[(size_t)p * NC + j] = bv;
    float fv = (float)bv;
    s += fv * fv;
  }
  for (int o = 32; o; o >>= 1) s += __shfl_xor(s, o);
  __shared__ float red[4];
  int lane = threadIdx.x & 63, wid = threadIdx.x >> 6;
  if (lane == 0) red[wid] = s;
  __syncthreads();
  if (threadIdx.x == 0) cn[j] = red[0] + red[1] + red[2] + red[3];
}

// ---------------- patch: LDS-staged im2col + rownorm (verified) ----------------
static constexpr int XS_STRIDE = 66;
static constexpr int XS_PLANE  = 64 * XS_STRIDE;
static constexpr int XS_OFF    = 2;

__global__ void __launch_bounds__(256, 4) patch_kernel(
    const float* __restrict__ x, bf16* __restrict__ flatB,
    float* __restrict__ rn, float* __restrict__ rsum) {
  __shared__ bf16 xs[XS_OFF + 3 * XS_PLANE + 64];
  const int bh = blockIdx.x;
  const int b = bh >> 6, h = bh & 63;
  const size_t bOff = (size_t)b * (C_IN * L_);
#pragma unroll
  for (int it = 0; it < 12; ++it) {
    int idx = threadIdx.x + it * 256;
    int plane = idx >> 10;
    int rem = idx & 1023;
    int c = rem >> 4;
    int f4 = rem & 15;
    int y = h + plane - 1;
    int e = XS_OFF + plane * XS_PLANE + c * XS_STRIDE + f4 * 4;
    bf16x2 lo = {(bf16)0.f, (bf16)0.f}, hi = {(bf16)0.f, (bf16)0.f};
    if ((unsigned)y < 64u) {
      float4 v = *(const float4*)(x + bOff + (size_t)c * L_ + y * 64 + f4 * 4);
      lo = bf16x2{(bf16)v.x, (bf16)v.y};
      hi = bf16x2{(bf16)v.z, (bf16)v.w};
    }
    *(bf16x2*)(xs + e) = lo;
    *(bf16x2*)(xs + e + 2) = hi;
  }
  __syncthreads();

  const int lane = threadIdx.x & 63, wid = threadIdx.x >> 6;
  int eb[8], km[8];
#pragma unroll
  for (int q = 0; q < 8; q++) {
    int p = lane * 8 + q;
    int c = p / 9, r9 = p - c * 9;
    int kh = r9 / 3, kw = r9 - kh * 3;
    eb[q] = kh * XS_PLANE + c * XS_STRIDE + (kw - 1);
    km[q] = kw - 1;
  }
  int ebt[8], kmt[8];
  {
    int pl = (lane & 7) * 8;
#pragma unroll
    for (int q = 0; q < 8; q++) {
      int p = 512 + pl + q;
      int c = p / 9, r9 = p - c * 9;
      int kh = r9 / 3, kw = r9 - kh * 3;
      ebt[q] = kh * XS_PLANE + c * XS_STRIDE + (kw - 1);
      kmt[q] = kw - 1;
    }
  }
  for (int it = 0; it < 16; ++it) {
    int w = wid * 16 + it;
    int row = bh * 64 + w;
    bf16* outp = flatB + (size_t)row * PS;
    float s = 0.f;
    bf16x8 v;
#pragma unroll
    for (int q = 0; q < 8; q++) {
      int xx = w + km[q];
      float fv = ((unsigned)xx < 64u) ? (float)xs[XS_OFF + eb[q] + w] : 0.f;
      v[q] = (bf16)fv;
      s += fv * fv;
    }
    *(bf16x8*)(outp + lane * 8) = v;
    if (lane < 8) {
      bf16x8 v2;
#pragma unroll
      for (int q = 0; q < 8; q++) {
        int xx = w + kmt[q];
        float fv = ((unsigned)xx < 64u) ? (float)xs[XS_OFF + ebt[q] + w] : 0.f;
        v2[q] = (bf16)fv;
        s += fv * fv;
      }
      *(bf16x8*)(outp + 512 + lane * 8) = v2;
    }
    for (int o = 32; o; o >>= 1) s += __shfl_xor(s, o);
    if (lane == 0) { rn[row] = s; rsum[row] = 0.f; }
  }
}

// ---------------- NT-GEMM: 256x128 tile, 8 waves, BK=64 -----------------------
// 2-barrier single-buffer skeleton (r12-verified), M-tile doubled: per-CU
// barrier-drain count halves (4 seq blocks x 9 tiles) at 16 waves/CU.
// Per-wave code identical to r12 (64x64 wave-tile, acc[4][4]); wave grid 4m x 2n.
// LDS [256|128][64], slot s of row r holds k-chunk (s ^ (r&7)); pre-swizzled
// global source, same XOR on read (0 conflicts — row&7 invariant).
// EPI 1: E = exp(-t*dist) bf16 + atomicAdd row sums.  EPI 2: final in-place.
template <int EPI, int GX>
__global__ void __launch_bounds__(512, 4) gemm_nt(
    const bf16* __restrict__ A, int lda, const bf16* __restrict__ Bm, int ldb,
    int M, int N, int Kd,
    const float* __restrict__ e0, const float* __restrict__ e1,
    const float* __restrict__ e2, const bf16* flatB,
    float* outF, bf16* outB, int ldc) {
  const int blk = blockIdx.x;
  const int xcd = blk & 7;
  const int k = blk >> 3;
  const int ypx = (gridDim.x >> 3) / GX;
  const int bx = k % GX;
  const int by = xcd * ypx + k / GX;
  const int m0 = by * 256, n0 = bx * 128;

  __shared__ bf16 As[256 * 64];   // 32 KB
  __shared__ bf16 Bs[128 * 64];   // 16 KB
  const int tid = threadIdx.x;
  const int lane = tid & 63;
  const int wid = tid >> 6;        // 0..7
  const int wr = wid >> 1;         // 0..3 (m)
  const int wc = wid & 1;          // 0..1 (n)

  const int srow = tid >> 3;       // 0..63
  const int sch = ((tid & 7) ^ (srow & 7)) * 8;
  const bf16* gA = A + (size_t)(m0 + srow) * lda + sch;
  const bf16* gB = Bm + (size_t)(n0 + srow) * ldb + sch;

  const int lrow = lane & 15;
  const int kq = lane >> 4;
  const int axor = lrow & 7;
  const int arow = (wr * 64 + lrow) * 64;
  const int brow = (wc * 64 + lrow) * 64;

  f32x4 acc[4][4];
#pragma unroll
  for (int i = 0; i < 4; i++)
#pragma unroll
    for (int j = 0; j < 4; j++) acc[i][j] = f32x4{0.f, 0.f, 0.f, 0.f};

  const int nk = Kd >> 6;
  for (int kt = 0; kt < nk; ++kt) {
    __syncthreads();
    const bf16* ga = gA + kt * 64;
    const bf16* gb = gB + kt * 64;
#pragma unroll
    for (int q = 0; q < 4; ++q)
      gload_lds16(ga + (size_t)(q * 64) * lda, As + q * 4096 + tid * 8);
#pragma unroll
    for (int q = 0; q < 2; ++q)
      gload_lds16(gb + (size_t)(q * 64) * ldb, Bs + q * 4096 + tid * 8);
    __syncthreads();  // drains vmcnt -> LDS tile ready
#pragma unroll
    for (int h = 0; h < 2; ++h) {
      const int cs = ((h * 4 + kq) ^ axor) * 8;
      bf16x8 af[4], bfr[4];
#pragma unroll
      for (int i = 0; i < 4; i++) af[i] = *(const bf16x8*)(As + arow + i * 1024 + cs);
#pragma unroll
      for (int j = 0; j < 4; j++) bfr[j] = *(const bf16x8*)(Bs + brow + j * 1024 + cs);
#pragma unroll
      for (int i = 0; i < 4; i++)
#pragma unroll
        for (int j = 0; j < 4; j++)
          acc[i][j] = __builtin_amdgcn_mfma_f32_16x16x32_bf16(af[i], bfr[j], acc[i][j], 0, 0, 0);
    }
  }

  const int rb = m0 + wr * 64 + kq * 4;  // D row = (lane>>4)*4 + reg
  const int cb = n0 + wc * 64 + lrow;    // D col = lane&15
  if constexpr (EPI == 1) {
    // e0 = rn, e1 = cn, e2 = temp; outB = E (bf16), outF = rsum (fp32 atomics)
    float t = e2[0];
#pragma unroll
    for (int i = 0; i < 4; i++) {
      float rowsum[4] = {0.f, 0.f, 0.f, 0.f};
#pragma unroll
      for (int j = 0; j < 4; j++) {
        int col = cb + j * 16;
        float cnv = e1[col];
#pragma unroll
        for (int r = 0; r < 4; r++) {
          int row = rb + i * 16 + r;
          float d2 = e0[row] + cnv - 2.f * acc[i][j][r];
          float e = __expf(-t * sqrtf(fmaxf(d2, 0.f)));
          outB[(size_t)row * ldc + col] = (bf16)e;
          rowsum[r] += e;
        }
      }
#pragma unroll
      for (int r = 0; r < 4; r++) {
        float s = rowsum[r];
        s += __shfl_xor(s, 1);
        s += __shfl_xor(s, 2);
        s += __shfl_xor(s, 4);
        s += __shfl_xor(s, 8);
        if (lrow == 0) atomicAdd(outF + rb + i * 16 + r, s);
      }
    }
  } else {
    // EPI 2: e0 = temp, e1 = rsum; flatB = flat (read), outB = flat (in-place)
    float t = e0[0];
    float inv = 1.f / (t + 1.f);
#pragma unroll
    for (int i = 0; i < 4; i++) {
      float arw[4];
#pragma unroll
      for (int r = 0; r < 4; r++) arw[r] = t * inv / e1[rb + i * 16 + r];
#pragma unroll
      for (int j = 0; j < 4; j++) {
        int col = cb + j * 16;
        if (col < N) {
#pragma unroll
          for (int r = 0; r < 4; r++) {
            int row = rb + i * 16 + r;
            float fl = (float)flatB[(size_t)row * PS + col];
            float v = acc[i][j][r] * arw[r] + fl * inv;
            outB[(size_t)row * ldc + col] = (bf16)v;
          }
        }
      }
    }
  }
}

// ---------------- gemm3: fused reinterpret-transpose + mask + conv (r12) ------
__global__ void __launch_bounds__(256, 4) gemm3_kernel(
    const bf16* __restrict__ A, const bf16* __restrict__ F,
    const float* __restrict__ bias, float* __restrict__ outF) {
  const size_t bz = blockIdx.z;
  const bf16* Fb = F + bz * (size_t)L_ * PS;   // viewed [576][4096]
  float* outp = outF + bz * (size_t)C_OUT * L_;
  const int n0 = blockIdx.x * 128;

  __shared__ bf16 As[128 * 64];
  __shared__ bf16 Bs[128 * 64];
  const int tid = threadIdx.x;
  const int lane = tid & 63;
  const int wid = tid >> 6;
  const int wr = wid >> 1, wc = wid & 1;

  const int srow = tid >> 3;
  const int sch = ((tid & 7) ^ (srow & 7)) * 8;
  const bf16* gA = A + (size_t)srow * PS + sch;
  bf16* lA = As + tid * 8;

  const int lrow = lane & 15;
  const int kq = lane >> 4;
  const int axor = lrow & 7;
  const int arow = (wr * 64 + lrow) * 64;
  const int brow = (wc * 64 + lrow) * 64;

  f32x4 acc[4][4];
#pragma unroll
  for (int i = 0; i < 4; i++)
#pragma unroll
    for (int j = 0; j < 4; j++) acc[i][j] = f32x4{0.f, 0.f, 0.f, 0.f};

  const int nk = PS / 64;   // 9
  for (int kt = 0; kt < nk; ++kt) {
    __syncthreads();
    const bf16* ga = gA + kt * 64;
#pragma unroll
    for (int q = 0; q < 4; ++q)
      gload_lds16(ga + (size_t)(q * 32) * PS, lA + q * 2048);
#pragma unroll
    for (int ps = 0; ps < 2; ++ps) {
      int id = tid + ps * 256;
      int pp = id >> 4;
      int lc = id & 15;
      int pl = 2 * pp;
      int pg = kt * 64 + pl;
      const bf16* s0 = Fb + (size_t)pg * L_ + n0 + lc * 8;
      bf16x8 v0 = *(const bf16x8*)s0;
      bf16x8 v1 = *(const bf16x8*)(s0 + L_);
      int l8 = n0 + lc * 8;
      int oh = l8 >> 6;
      bool ow0 = (l8 & 63) == 0;
      int r90 = pg % 9;
      int kh0 = r90 / 3, kw0 = r90 - 3 * kh0;
      int r91 = (pg + 1) % 9;
      int kh1 = r91 / 3, kw1 = r91 - 3 * kh1;
      if (oh == 0 && kh0 == 0) {
#pragma unroll
        for (int e = 0; e < 8; e++) v0[e] = (bf16)0.f;
      }
      if (ow0 && kw0 == 0) v0[0] = (bf16)0.f;
      if (oh == 0 && kh1 == 0) {
#pragma unroll
        for (int e = 0; e < 8; e++) v1[e] = (bf16)0.f;
      }
      if (ow0 && kw1 == 0) v1[0] = (bf16)0.f;
#pragma unroll
      for (int e = 0; e < 8; ++e) {
        int l = lc * 8 + e;
        int addr = l * 64 + (((pl >> 3) ^ (l & 7)) << 3) + (pl & 7);
        *(bf16x2*)(Bs + addr) = bf16x2{v0[e], v1[e]};
      }
    }
    __syncthreads();
#pragma unroll
    for (int h = 0; h < 2; ++h) {
      const int cs = ((h * 4 + kq) ^ axor) * 8;
      bf16x8 af[4], bfr[4];
#pragma unroll
      for (int i = 0; i < 4; i++) af[i] = *(const bf16x8*)(As + arow + i * 1024 + cs);
#pragma unroll
      for (int j = 0; j < 4; j++) bfr[j] = *(const bf16x8*)(Bs + brow + j * 1024 + cs);
#pragma unroll
      for (int i = 0; i < 4; i++)
#pragma unroll
        for (int j = 0; j < 4; j++)
          acc[i][j] = __builtin_amdgcn_mfma_f32_16x16x32_bf16(af[i], bfr[j], acc[i][j], 0, 0, 0);
    }
  }

  const int rb = wr * 64 + kq * 4;
  const int cb = n0 + wc * 64 + lrow;
#pragma unroll
  for (int i = 0; i < 4; i++) {
#pragma unroll
    for (int j = 0; j < 4; j++) {
      int col = cb + j * 16;
#pragma unroll
      for (int r = 0; r < 4; r++) {
        int row = rb + i * 16 + r;
        outp[(size_t)row * L_ + col] = acc[i][j][r] + bias[row];
      }
    }
  }
}

// ---------------- launch ----------------

extern "C" void kernel_launch(void* const* d_in, const int* in_sizes, int n_in,
                              void* d_out, int out_size, void* d_ws, size_t ws_size,
                              hipStream_t stream) {
  (void)in_sizes; (void)n_in; (void)out_size; (void)ws_size;
  const float* x    = (const float*)d_in[0];
  const float* cc   = (const float*)d_in[1];
  const float* tp   = (const float*)d_in[2];
  const float* w    = (const float*)d_in[3];
  const float* bias = (const float*)d_in[4];
  float* out = (float*)d_out;

  char* ws = (char*)d_ws;
  size_t off = 0;
  auto alloc = [&](size_t bytes) {
    char* p = ws + off;
    off += (bytes + 255) & ~(size_t)255;
    return p;
  };
  bf16* ccB   = (bf16*)alloc((size_t)NC * PS * 2);        // 0.59 MB
  bf16* ccT   = (bf16*)alloc((size_t)640 * NC * 2);       // 0.66 MB (576 + 64 zero pad)
  float* cn   = (float*)alloc((size_t)NC * 4);
  bf16* WB    = (bf16*)alloc((size_t)C_OUT * PS * 2);     // 0.15 MB
  float* rn   = (float*)alloc((size_t)NR * 4);            // 0.26 MB
  float* rsum = (float*)alloc((size_t)NR * 4);            // 0.26 MB
  bf16* flatB = (bf16*)alloc((size_t)NR * PS * 2);        // 75.5 MB (final in-place)
  bf16* E     = (bf16*)alloc((size_t)NR * NC * 2);        // 67.1 MB
  // total ~= 145 MB  (ws_size = 256 MiB)

  prep_w_kernel<<<dim3(288), dim3(256), 0, stream>>>(w, WB, ccT);
  prep_cc_kernel<<<dim3(NC), dim3(256), 0, stream>>>(cc, ccB, ccT, cn);
  patch_kernel<<<dim3(B_ * H_), dim3(256), 0, stream>>>(x, flatB, rn, rsum);
  // GEMM1 (+softmax numerator): E = exp(-t*sqrt(max(rn+cn-2*flat@cc^T,0))), rsum += rows
  gemm_nt<1, 4><<<dim3((NR / 256) * (NC / 128)), dim3(512), 0, stream>>>(
      flatB, PS, ccB, PS, NR, NC, PS, rn, cn, tp, nullptr, rsum, E, NC);
  // GEMM2: flat <- (t*(E@cc)/rsum + flat)/(t+1)   (in-place; 5 n-tiles over 640-pad)
  gemm_nt<2, 5><<<dim3((NR / 256) * 5), dim3(512), 0, stream>>>(
      E, NC, ccT, NC, NR, PS, NC, tp, rsum, nullptr, flatB, nullptr, flatB, PS);
  // GEMM3 (batched, fused transpose+mask): out[b] = W' @ (mask o view(final_b)) + bias
  gemm3_kernel<<<dim3(L_ / 128, 1, B_), dim3(256), 0, stream>>>(WB, flatB, bias, out);
}